// Round 9
// baseline (1062.267 us; speedup 1.0000x reference)
//
#include <hip/hip_runtime.h>
#include <cstddef>

#define DEV __device__ __forceinline__

DEV float fexp2(float x) { return __builtin_amdgcn_exp2f(x); }
DEV float frcp(float x)  { return __builtin_amdgcn_rcpf(x); }
DEV float fsigm(float x) { return frcp(1.0f + fexp2(-1.44269504f * x)); }
DEV float ftanh_(float x){ return 1.0f - 2.0f * frcp(1.0f + fexp2(2.88539008f * x)); }

typedef _Float16 h2t __attribute__((ext_vector_type(2)));
typedef _Float16 v8h __attribute__((ext_vector_type(8)));
typedef float v4f __attribute__((ext_vector_type(4)));
union U32H2 { unsigned int u; h2t h; };
DEV h2t u2h(unsigned int u) { U32H2 x; x.u = u; return x.h; }

// ---------------------------------------------------------------------------
// f16 MFMA GEMM: C[M,N] = A[M,K] @ W[N,K]^T + bias; A,W f16 row-major.
// BM in {64,128}, BK=32, 256 threads (4 waves, 2x2), wave tile (BM/2)x(BN/2).
// GATHER: A row r=(b,t) reads row target[b,t-1] of A (zeros for t=0).
// ---------------------------------------------------------------------------
template <int BM, int BN, bool RELU, bool OUTF16, bool GATHER>
__global__ __launch_bounds__(256) void hgemm_kernel(
    const _Float16* __restrict__ A, const _Float16* __restrict__ W,
    const float* __restrict__ bias1, void* __restrict__ Cout,
    int M, int N, int K, const int* __restrict__ target)
{
    constexpr int MT = BM / 32;
    constexpr int NT = BN / 32;
    constexpr int RA = BM / 64;
    constexpr int RB = BN / 64;
    __shared__ _Float16 As[BM * 32];
    __shared__ _Float16 Bs[BN * 32];

    const int tid = threadIdx.x;
    const int lane = tid & 63;
    const int lm = lane & 15, lq = lane >> 4;
    const int wrow = ((tid >> 6) & 1) * (BM / 2);
    const int wcol = (tid >> 7) * (BN / 2);
    const int m0 = blockIdx.x * BM, n0 = blockIdx.y * BN;
    const _Float16* Wb = W + (size_t)n0 * K;

    v4f acc[MT][NT];
#pragma unroll
    for (int i = 0; i < MT; ++i)
#pragma unroll
        for (int j = 0; j < NT; ++j) acc[i][j] = (v4f){0.f, 0.f, 0.f, 0.f};

    const int rowS = tid >> 2, qS = tid & 3;

    // A source rows (gather-aware, fixed across k)
    size_t arow[RA]; bool az[RA];
#pragma unroll
    for (int r = 0; r < RA; ++r) {
        int row = m0 + rowS + 64 * r;
        if (GATHER) {
            int b = row >> 8, t = row & 255;
            if (t == 0) { az[r] = true; arow[r] = 0; }
            else { az[r] = false;
                   arow[r] = (size_t)((b << 8) + target[(b << 8) + t - 1]); }
        } else { az[r] = false; arow[r] = (size_t)row; }
    }
    const uint4 z4 = {0u, 0u, 0u, 0u};

    uint4 ra[RA], rb[RB];
#pragma unroll
    for (int r = 0; r < RA; ++r)
        ra[r] = az[r] ? z4 : *(const uint4*)(A + arow[r] * K + qS * 8);
#pragma unroll
    for (int r = 0; r < RB; ++r)
        rb[r] = *(const uint4*)(Wb + (size_t)(rowS + 64 * r) * K + qS * 8);

    for (int k0 = 0; k0 < K; k0 += 32) {
        __syncthreads();
#pragma unroll
        for (int r = 0; r < RA; ++r)
            *(uint4*)(As + (size_t)(tid + 256 * r) * 8) = ra[r];
#pragma unroll
        for (int r = 0; r < RB; ++r)
            *(uint4*)(Bs + (size_t)(tid + 256 * r) * 8) = rb[r];
        __syncthreads();
        int kn = k0 + 32;
        if (kn < K) {
#pragma unroll
            for (int r = 0; r < RA; ++r)
                ra[r] = az[r] ? z4 : *(const uint4*)(A + arow[r] * K + kn + qS * 8);
#pragma unroll
            for (int r = 0; r < RB; ++r)
                rb[r] = *(const uint4*)(Wb + (size_t)(rowS + 64 * r) * K + kn + qS * 8);
        }
        v8h af[MT], bf[NT];
#pragma unroll
        for (int i = 0; i < MT; ++i)
            af[i] = *(const v8h*)(As + (size_t)(wrow + i * 16 + lm) * 32 + lq * 8);
#pragma unroll
        for (int j = 0; j < NT; ++j)
            bf[j] = *(const v8h*)(Bs + (size_t)(wcol + j * 16 + lm) * 32 + lq * 8);
#pragma unroll
        for (int i = 0; i < MT; ++i)
#pragma unroll
            for (int j = 0; j < NT; ++j)
                acc[i][j] = __builtin_amdgcn_mfma_f32_16x16x32_f16(
                    af[i], bf[j], acc[i][j], 0, 0, 0);
    }

#pragma unroll
    for (int j = 0; j < NT; ++j) {
        int col = n0 + wcol + j * 16 + lm;
        float bv = bias1[col];
#pragma unroll
        for (int i = 0; i < MT; ++i) {
            int rbase = m0 + wrow + i * 16 + lq * 4;
#pragma unroll
            for (int rg = 0; rg < 4; ++rg) {
                float vv = acc[i][j][rg] + bv;
                if (RELU) vv = fmaxf(vv, 0.f);
                if (OUTF16)
                    ((_Float16*)Cout)[(size_t)(rbase + rg) * N + col] = (_Float16)vv;
                else
                    ((float*)Cout)[(size_t)(rbase + rg) * N + col] = vv;
            }
        }
    }
}

// ---------------------------------------------------------------------------
// Fused weight conversion. Wih dest rows gate-interleaved: dest row
// j*4+g = src row g*256+j.
// ---------------------------------------------------------------------------
__global__ __launch_bounds__(256) void cvt_all_kernel(
    const float* __restrict__ s0, const float* __restrict__ s1,
    const float* __restrict__ s2, const float* __restrict__ s3,
    const float* __restrict__ s4, const float* __restrict__ s5,
    _Float16* __restrict__ dst)
{
    int i = blockIdx.x * 256 + threadIdx.x;
    if (i >= 1900544) return;
    float val;
    if (i < 589824)       val = s0[i];
    else if (i < 786432)  val = s1[i - 589824];
    else if (i < 1179648) val = s2[i - 786432];
    else if (i < 1572864) val = s3[i - 1179648];
    else if (i < 1835008) {
        int idx = i - 1572864;
        int rp = idx >> 8, k = idx & 255;
        int j = rp >> 2, g = rp & 3;
        val = s4[(g * 256 + j) * 256 + k];
    }
    else                  val = s5[i - 1835008];
    dst[i] = (_Float16)val;
}

// ---------------------------------------------------------------------------
__global__ __launch_bounds__(64) void bin_enc_kernel(
    const float* __restrict__ bin_info, const float* __restrict__ W1,
    const float* __restrict__ b1, const float* __restrict__ W2,
    const float* __restrict__ b2, float* __restrict__ BBo)
{
    int b = blockIdx.x, d = threadIdx.x;
    __shared__ float h1[64];
    float x0 = bin_info[b * 2], x1 = bin_info[b * 2 + 1];
    h1[d] = fmaxf(W1[d * 2] * x0 + W1[d * 2 + 1] * x1 + b1[d], 0.f);
    __syncthreads();
    float acc = b2[d];
#pragma unroll 4
    for (int e = 0; e < 64; ++e) acc += W2[d * 64 + e] * h1[e];
    BBo[b * 64 + d] = acc;
}

// ---------------------------------------------------------------------------
__global__ __launch_bounds__(128) void part_enc_kernel(
    const float* __restrict__ parts, const float* __restrict__ W1,
    const float* __restrict__ b1, const float* __restrict__ W2,
    const float* __restrict__ b2, const float* __restrict__ BBi,
    const float* __restrict__ pos_emb, float* __restrict__ X,
    _Float16* __restrict__ X16)
{
    __shared__ float W2s[128][129];
    __shared__ float h1[128];
    __shared__ float pin[16];
    int tid = threadIdx.x;
    int b = blockIdx.x >> 3, s0 = (blockIdx.x & 7) * 32;
    for (int l = 0; l < 128; ++l) W2s[l][tid] = W2[l * 128 + tid];
    float w1r[16];
#pragma unroll
    for (int k = 0; k < 16; ++k) w1r[k] = W1[tid * 16 + k];
    float bias1v = b1[tid], bias2v = b2[tid];
    for (int si = 0; si < 32; ++si) {
        int s = s0 + si;
        size_t row = (size_t)b * 256 + s;
        if (tid < 16) pin[tid] = parts[row * 16 + tid];
        __syncthreads();
        float h = bias1v;
#pragma unroll
        for (int k = 0; k < 16; ++k) h += w1r[k] * pin[k];
        h1[tid] = fmaxf(h, 0.f);
        __syncthreads();
        float acc = bias2v;
#pragma unroll 4
        for (int e = 0; e < 128; ++e) acc += W2s[tid][e] * h1[e];
        X[row * 256 + tid] = acc;
        X16[row * 256 + tid] = (_Float16)acc;
        if (tid < 64) {
            float bbv = BBi[b * 64 + tid];
            float pev = pos_emb[s * 64 + tid];
            X[row * 256 + 128 + tid] = bbv;
            X[row * 256 + 192 + tid] = pev;
            X16[row * 256 + 128 + tid] = (_Float16)bbv;
            X16[row * 256 + 192 + tid] = (_Float16)pev;
        }
        __syncthreads();
    }
}

// ---------------------------------------------------------------------------
// MFMA attention: one block per (b,h), 256 threads (4 waves).
// ---------------------------------------------------------------------------
__global__ __launch_bounds__(256) void attn_mfma_kernel(
    const _Float16* __restrict__ QKV, _Float16* __restrict__ O16)
{
    int bh = blockIdx.x;
    int b = bh >> 3, h = bh & 7;
    const int tid = threadIdx.x;
    const int w = tid >> 6;
    const int lane = tid & 63;
    const int lm = lane & 15, lq = lane >> 4;
    const float c_se = 0.17677669529663687f * 1.44269504f;

    __shared__ _Float16 Ks[4][256][8];
    __shared__ _Float16 Vt[32][264];
    __shared__ _Float16 Ps[4][16][264];

    const _Float16* qkvb = QKV + (size_t)(b * 256) * 768 + h * 32;
    {
        int s = tid;
        const _Float16* kr = qkvb + (size_t)s * 768 + 256;
#pragma unroll
        for (int c = 0; c < 4; ++c)
            *(uint4*)&Ks[c][s][0] = *(const uint4*)(kr + c * 8);
        const _Float16* vr = qkvb + (size_t)s * 768 + 512;
        _Float16 vtmp[32];
        *(uint4*)&vtmp[0]  = *(const uint4*)(vr);
        *(uint4*)&vtmp[8]  = *(const uint4*)(vr + 8);
        *(uint4*)&vtmp[16] = *(const uint4*)(vr + 16);
        *(uint4*)&vtmp[24] = *(const uint4*)(vr + 24);
#pragma unroll
        for (int d = 0; d < 32; ++d) Vt[d][s] = vtmp[d];
    }
    __syncthreads();

#pragma unroll 1
    for (int st = 0; st < 4; ++st) {
        int rt = w * 4 + st;
        v8h qf = *(const v8h*)(QKV + (size_t)(b * 256 + rt * 16 + lm) * 768
                               + h * 32 + lq * 8);
        v4f acc[16];
#pragma unroll
        for (int ct = 0; ct < 16; ++ct) {
            v8h kf = *(const v8h*)&Ks[lq][ct * 16 + lm][0];
            acc[ct] = __builtin_amdgcn_mfma_f32_16x16x32_f16(
                qf, kf, (v4f){0.f, 0.f, 0.f, 0.f}, 0, 0, 0);
        }
        float sminv[4];
#pragma unroll
        for (int r = 0; r < 4; ++r) {
            float m = acc[0][r];
#pragma unroll
            for (int ct = 1; ct < 16; ++ct) m = fmaxf(m, acc[ct][r]);
#pragma unroll
            for (int msk = 1; msk < 16; msk <<= 1)
                m = fmaxf(m, __shfl_xor(m, msk));
            float ssum = 0.f;
#pragma unroll
            for (int ct = 0; ct < 16; ++ct) {
                float e = fexp2((acc[ct][r] - m) * c_se);
                acc[ct][r] = e;
                ssum += e;
            }
#pragma unroll
            for (int msk = 1; msk < 16; msk <<= 1)
                ssum += __shfl_xor(ssum, msk);
            sminv[r] = frcp(ssum);
        }
#pragma unroll
        for (int ct = 0; ct < 16; ++ct)
#pragma unroll
            for (int r = 0; r < 4; ++r)
                Ps[w][lq * 4 + r][ct * 16 + lm] =
                    (_Float16)(acc[ct][r] * sminv[r]);
#pragma unroll
        for (int dt = 0; dt < 2; ++dt) {
            v4f o = (v4f){0.f, 0.f, 0.f, 0.f};
#pragma unroll
            for (int jc = 0; jc < 8; ++jc) {
                v8h pf = *(const v8h*)&Ps[w][lm][jc * 32 + lq * 8];
                v8h vf = *(const v8h*)&Vt[dt * 16 + lm][jc * 32 + lq * 8];
                o = __builtin_amdgcn_mfma_f32_16x16x32_f16(pf, vf, o, 0, 0, 0);
            }
#pragma unroll
            for (int r = 0; r < 4; ++r)
                O16[(size_t)(b * 256 + rt * 16 + lq * 4 + r) * 256
                    + h * 32 + dt * 16 + lm] = (_Float16)o[r];
        }
    }
}

// ---------------------------------------------------------------------------
// Residual add + LayerNorm, wave-per-row. grid = rows/4.
// ---------------------------------------------------------------------------
__global__ __launch_bounds__(256) void add_ln_kernel(
    float* __restrict__ X, const float* __restrict__ R,
    const float* __restrict__ g, const float* __restrict__ beta,
    _Float16* __restrict__ X16)
{
    int row = blockIdx.x * 4 + (threadIdx.x >> 6);
    int lane = threadIdx.x & 63;
    size_t base = (size_t)row * 256 + lane * 4;
    float4 xv = *(const float4*)&X[base];
    float4 rv = *(const float4*)&R[base];
    float y0 = xv.x + rv.x, y1 = xv.y + rv.y;
    float y2 = xv.z + rv.z, y3 = xv.w + rv.w;
    float s = y0 + y1 + y2 + y3;
    float s2 = y0 * y0 + y1 * y1 + y2 * y2 + y3 * y3;
#pragma unroll
    for (int m = 1; m < 64; m <<= 1) {
        s += __shfl_xor(s, m);
        s2 += __shfl_xor(s2, m);
    }
    float mean = s * (1.f / 256.f);
    float var = s2 * (1.f / 256.f) - mean * mean;
    float inv = rsqrtf(var + 1e-5f);
    float4 gv = *(const float4*)&g[lane * 4];
    float4 bv = *(const float4*)&beta[lane * 4];
    float o0 = (y0 - mean) * inv * gv.x + bv.x;
    float o1 = (y1 - mean) * inv * gv.y + bv.y;
    float o2 = (y2 - mean) * inv * gv.z + bv.z;
    float o3 = (y3 - mean) * inv * gv.w + bv.w;
    *(float4*)&X[base] = make_float4(o0, o1, o2, o3);
    U32H2 a, c;
    a.h = h2t{(_Float16)o0, (_Float16)o1};
    c.h = h2t{(_Float16)o2, (_Float16)o3};
    uint2 u; u.x = a.u; u.y = c.u;
    *(uint2*)(X16 + base) = u;
}

// ---------------------------------------------------------------------------
// Whh fp32 [1024,256] -> f16x2 blob; split: LDS 8 words (c<2), regs 44
// (2<=c<13), stream 12 (13<=c<16). Also builds permuted lstm bias PB.
// ---------------------------------------------------------------------------
__global__ __launch_bounds__(256) void wcvt2_kernel(
    const float* __restrict__ Whh, unsigned int* __restrict__ WB,
    const float* __restrict__ bih, const float* __restrict__ bhh,
    float* __restrict__ PB)
{
    int idx = blockIdx.x * 256 + threadIdx.x;  // 0..131071
    if (idx < 1024) {
        int j = idx >> 2, g = idx & 3;
        PB[idx] = bih[g * 256 + j] + bhh[g * 256 + j];
    }
    int l = idx & 3;
    int gt = idx >> 2;
    int tid = gt & 511;
    int q = gt >> 9;                            // 0..63
    int i, c;
    if (q < 8)       { i = q >> 1; c = q & 1; }
    else if (q < 52) { int qq = q - 8; i = qq / 11; c = 2 + qq % 11; }
    else             { int qq = q - 52; c = 13 + (qq >> 2); i = qq & 3; }
    int r = ((tid & 255) << 2) + i;
    int k = ((tid >> 8) << 7) + (c << 3) + (l << 1);
    _Float16 lo = (_Float16)Whh[r * 256 + k];
    _Float16 hi = (_Float16)Whh[r * 256 + k + 1];
    U32H2 x; x.h = h2t{lo, hi};
    WB[idx] = x.u;
}

// ---------------------------------------------------------------------------
// LSTM recurrence: 1 block/batch, 512 threads. Weights: 64 KB LDS +
// reg slab + 96 KB/step L2 stream. g_in f16 gate-interleaved [t][j*4+g].
// ---------------------------------------------------------------------------
__global__ __launch_bounds__(512) void lstm_kernel(
    const _Float16* __restrict__ g_in, const uint4* __restrict__ WB4,
    _Float16* __restrict__ HALL16)
{
    const int b = blockIdx.x;
    const int tid = threadIdx.x;
    const int kh = tid >> 8, j4 = tid & 255;

    __shared__ uint4 WL4[4096];        // 64 KB
    __shared__ float gpart[2][1024];   // 8 KB
    __shared__ uint4 h2v[32];          // 512 B
    unsigned int* h2_s = (unsigned int*)h2v;

#pragma unroll
    for (int g = 0; g < 8; ++g) WL4[g * 512 + tid] = WB4[g * 512 + tid];
    uint4 wr[44];
#pragma unroll
    for (int q = 0; q < 44; ++q) wr[q] = WB4[(8 + q) * 512 + tid];
    if (tid < 128) h2_s[tid] = 0u;

    const _Float16* ginb = g_in + (size_t)b * 256 * 1024;
    uint2 gi = make_uint2(0u, 0u);
    if (tid < 256) gi = *(const uint2*)(ginb + tid * 4);
    float c_state = 0.f;
    const uint4* SW4 = WB4 + 52 * 512;
    __syncthreads();

    for (int t = 0; t < 256; ++t) {
        uint4 sw[12];
#pragma unroll
        for (int q = 0; q < 4; ++q) sw[q] = SW4[q * 512 + tid];

        float acc[4] = {0.f, 0.f, 0.f, 0.f};
#pragma unroll
        for (int c = 0; c < 16; ++c) {
            if (c == 2) {
#pragma unroll
                for (int q = 4; q < 8; ++q) sw[q] = SW4[q * 512 + tid];
            }
            if (c == 6) {
#pragma unroll
                for (int q = 8; q < 12; ++q) sw[q] = SW4[q * 512 + tid];
            }
            uint4 h4 = h2v[(kh << 4) + c];
            h2t hx = u2h(h4.x), hy = u2h(h4.y), hz = u2h(h4.z), hw = u2h(h4.w);
#pragma unroll
            for (int i = 0; i < 4; ++i) {
                uint4 w = (c < 2)  ? WL4[((i << 1) + c) * 512 + tid]
                        : (c < 13) ? wr[i * 11 + (c - 2)]
                                   : sw[((c - 13) << 2) + i];
                acc[i] = __builtin_amdgcn_fdot2(u2h(w.x), hx, acc[i], false);
                acc[i] = __builtin_amdgcn_fdot2(u2h(w.y), hy, acc[i], false);
                acc[i] = __builtin_amdgcn_fdot2(u2h(w.z), hz, acc[i], false);
                acc[i] = __builtin_amdgcn_fdot2(u2h(w.w), hw, acc[i], false);
            }
        }
        *(float4*)&gpart[kh][j4 << 2] = make_float4(acc[0], acc[1], acc[2], acc[3]);
        __syncthreads();

        if (tid < 256) {
            int j = tid;
            h2t p0 = u2h(gi.x), p1 = u2h(gi.y);
            float ig = (float)p0.x + gpart[0][j]       + gpart[1][j];
            float fg = (float)p0.y + gpart[0][j + 256] + gpart[1][j + 256];
            float gg = (float)p1.x + gpart[0][j + 512] + gpart[1][j + 512];
            float og = (float)p1.y + gpart[0][j + 768] + gpart[1][j + 768];
            c_state = fsigm(fg) * c_state + fsigm(ig) * ftanh_(gg);
            float h = fsigm(og) * ftanh_(c_state);
            HALL16[((size_t)(b * 256 + t)) * 256 + j] = (_Float16)h;
            U32H2 hxp; hxp.h = h2t{(_Float16)h, (_Float16)0.f};
            unsigned int hu = hxp.u & 0xffffu;
            unsigned int other = (unsigned int)__shfl_xor((int)hu, 1);
            if ((j & 1) == 0) h2_s[j >> 1] = hu | (other << 16);
            int tn = (t < 255) ? (t + 1) : 255;
            gi = *(const uint2*)(ginb + (size_t)tn * 1024 + j * 4);
        }
        __syncthreads();
    }
}

// ---------------------------------------------------------------------------
// Pointer logits, register-blocked: 64x64 tile per block, 512 threads,
// thread = 4t x 2i. hp staged [t][d] (broadcast float4 reads), ep staged
// transposed [d][i] (+2 pad, conflict-free float2), v pre-doubled.
// out = vsum - sum_d 2*v_d / (1 + exp2(2.88539*(hp+ep))).
// ---------------------------------------------------------------------------
__global__ __launch_bounds__(512) void pointer_kernel(
    const float* __restrict__ HP, const float* __restrict__ EP,
    const float* __restrict__ v, float* __restrict__ out)
{
    int b = blockIdx.z, tt = blockIdx.y, it = blockIdx.x;
    __shared__ float hp_s[64][256];
    __shared__ float ep_t[256][66];
    __shared__ float v2_s[256];
    __shared__ float redv[8];
    const int tid = threadIdx.x;
    const float cs = 2.88539008f;
    const float* hpb = HP + ((size_t)b * 256 + tt * 64) * 256;
    const float* epb = EP + ((size_t)b * 256 + it * 64) * 256;
#pragma unroll
    for (int l = 0; l < 8; ++l) {
        int idx = tid + l * 512;           // 0..4095
        int r = idx >> 6, c4 = idx & 63;
        float4 hv = *(const float4*)(hpb + r * 256 + c4 * 4);
        hv.x *= cs; hv.y *= cs; hv.z *= cs; hv.w *= cs;
        *(float4*)&hp_s[r][c4 * 4] = hv;
        float4 ev = *(const float4*)(epb + r * 256 + c4 * 4);
        ep_t[c4 * 4 + 0][r] = ev.x * cs;
        ep_t[c4 * 4 + 1][r] = ev.y * cs;
        ep_t[c4 * 4 + 2][r] = ev.z * cs;
        ep_t[c4 * 4 + 3][r] = ev.w * cs;
    }
    float vp = 0.f;
    if (tid < 256) {
        float vv = v[tid];
        v2_s[tid] = 2.0f * vv;
        vp = vv;
    }
#pragma unroll
    for (int m = 1; m < 64; m <<= 1) vp += __shfl_xor(vp, m);
    if ((tid & 63) == 0) redv[tid >> 6] = vp;
    __syncthreads();
    float vsum = redv[0] + redv[1] + redv[2] + redv[3]
               + redv[4] + redv[5] + redv[6] + redv[7];

    const int tl = tid >> 5, il = tid & 31;  // 16 t-groups x 32 i-groups
    const int t0 = tl * 4, i0 = il * 2;
    float acc[4][2];
#pragma unroll
    for (int r = 0; r < 4; ++r) { acc[r][0] = 0.f; acc[r][1] = 0.f; }

#pragma unroll 4
    for (int dq = 0; dq < 64; ++dq) {
        float4 h0 = *(const float4*)&hp_s[t0 + 0][dq * 4];
        float4 h1 = *(const float4*)&hp_s[t0 + 1][dq * 4];
        float4 h2 = *(const float4*)&hp_s[t0 + 2][dq * 4];
        float4 h3 = *(const float4*)&hp_s[t0 + 3][dq * 4];
        float4 vq = *(const float4*)&v2_s[dq * 4];
        float hr[4][4] = {{h0.x, h0.y, h0.z, h0.w}, {h1.x, h1.y, h1.z, h1.w},
                          {h2.x, h2.y, h2.z, h2.w}, {h3.x, h3.y, h3.z, h3.w}};
        float vj[4] = {vq.x, vq.y, vq.z, vq.w};
#pragma unroll
        for (int j = 0; j < 4; ++j) {
            float2 ev = *(const float2*)&ep_t[dq * 4 + j][i0];
#pragma unroll
            for (int r = 0; r < 4; ++r) {
                float s0 = hr[r][j] + ev.x;
                float s1 = hr[r][j] + ev.y;
                acc[r][0] = fmaf(vj[j], frcp(1.0f + fexp2(s0)), acc[r][0]);
                acc[r][1] = fmaf(vj[j], frcp(1.0f + fexp2(s1)), acc[r][1]);
            }
        }
    }
#pragma unroll
    for (int r = 0; r < 4; ++r) {
        float2 o;
        o.x = vsum - acc[r][0];
        o.y = vsum - acc[r][1];
        *(float2*)&out[((size_t)b * 256 + tt * 64 + t0 + r) * 256
                       + it * 64 + i0] = o;
    }
}

// ---------------------------------------------------------------------------
extern "C" void kernel_launch(void* const* d_in, const int* in_sizes, int n_in,
                              void* d_out, int out_size, void* d_ws, size_t ws_size,
                              hipStream_t stream)
{
    const float* parts    = (const float*)d_in[0];
    const float* bin_info = (const float*)d_in[1];
    const int*   target   = (const int*)d_in[2];
    const float* pe_W1 = (const float*)d_in[3];
    const float* pe_b1 = (const float*)d_in[4];
    const float* pe_W2 = (const float*)d_in[5];
    const float* pe_b2 = (const float*)d_in[6];
    const float* be_W1 = (const float*)d_in[7];
    const float* be_b1 = (const float*)d_in[8];
    const float* be_W2 = (const float*)d_in[9];
    const float* be_b2 = (const float*)d_in[10];
    const float* pos_emb = (const float*)d_in[11];
    const float* tr_Wqkv = (const float*)d_in[12];
    const float* tr_bqkv = (const float*)d_in[13];
    const float* tr_Wo   = (const float*)d_in[14];
    const float* tr_bo   = (const float*)d_in[15];
    const float* tr_ln1_g = (const float*)d_in[16];
    const float* tr_ln1_b = (const float*)d_in[17];
    const float* tr_ff_W1 = (const float*)d_in[18];
    const float* tr_ff_b1 = (const float*)d_in[19];
    const float* tr_ff_W2 = (const float*)d_in[20];
    const float* tr_ff_b2 = (const float*)d_in[21];
    const float* tr_ln2_g = (const float*)d_in[22];
    const float* tr_ln2_b = (const float*)d_in[23];
    const float* lstm_Wih = (const float*)d_in[24];
    const float* lstm_Whh = (const float*)d_in[25];
    const float* lstm_bih = (const float*)d_in[26];
    const float* lstm_bhh = (const float*)d_in[27];
    const float* ptr_W = (const float*)d_in[28];
    const float* ptr_b = (const float*)d_in[29];
    const float* ptr_v = (const float*)d_in[30];

    // ---- workspace layout (floats) ----
    float* ws = (float*)d_ws;
    float* X     = ws;                        // 2,097,152
    float* S1    = X + 2097152;               // 8,388,608 (qkv/ff1/g_in f16)
    float* CF32  = S1 + 8388608;              // 2,097,152
    float* EPROJ = CF32 + 2097152;            // 2,097,152
    float* X16f  = EPROJ + 2097152;           // 1,048,576
    float* S2f   = X16f + 1048576;            // 1,048,576
    float* W16f  = S2f + 1048576;             // 1,048,576
    float* WBf   = W16f + 1048576;            // 131,072
    float* BBuf  = WBf + 131072;              // 2,048
    float* PB    = BBuf + 2048;               // 1,024

    _Float16* X16    = (_Float16*)X16f;
    _Float16* S2h    = (_Float16*)S2f;
    _Float16* HALL16 = S2h;
    _Float16* S1h    = (_Float16*)S1;
    _Float16* W16    = (_Float16*)W16f;
    _Float16* Wqkv16 = W16;                   // 589,824
    _Float16* Wo16   = Wqkv16 + 589824;       // 196,608
    _Float16* Wff116 = Wo16 + 196608;         // 393,216
    _Float16* Wff216 = Wff116 + 393216;       // 393,216
    _Float16* Wih16  = Wff216 + 393216;       // 262,144 (gate-interleaved rows)
    _Float16* WpW16  = Wih16 + 262144;        // 65,536

    // ---- one-time weight conversions ----
    cvt_all_kernel<<<7424, 256, 0, stream>>>(tr_Wqkv, tr_Wo, tr_ff_W1, tr_ff_W2,
                                             lstm_Wih, ptr_W, W16);
    wcvt2_kernel<<<512, 256, 0, stream>>>(lstm_Whh, (unsigned int*)WBf,
                                          lstm_bih, lstm_bhh, PB);

    // ---- encoders ----
    bin_enc_kernel<<<32, 64, 0, stream>>>(bin_info, be_W1, be_b1, be_W2, be_b2, BBuf);
    part_enc_kernel<<<256, 128, 0, stream>>>(parts, pe_W1, pe_b1, pe_W2, pe_b2,
                                             BBuf, pos_emb, X, X16);

    // ---- transformer layers ----
    for (int l = 0; l < 3; ++l) {
        hgemm_kernel<64, 128, false, true, false><<<dim3(128, 6), 256, 0, stream>>>(
            X16, Wqkv16 + (size_t)l * 196608, tr_bqkv + l * 768,
            S1h, 8192, 768, 256, nullptr);
        attn_mfma_kernel<<<256, 256, 0, stream>>>(S1h, S2h);
        hgemm_kernel<64, 64, false, false, false><<<dim3(128, 4), 256, 0, stream>>>(
            S2h, Wo16 + (size_t)l * 65536, tr_bo + l * 256,
            CF32, 8192, 256, 256, nullptr);
        add_ln_kernel<<<2048, 256, 0, stream>>>(X, CF32, tr_ln1_g + l * 256,
                                                tr_ln1_b + l * 256, X16);
        hgemm_kernel<64, 128, true, true, false><<<dim3(128, 4), 256, 0, stream>>>(
            X16, Wff116 + (size_t)l * 131072, tr_ff_b1 + l * 512,
            S1h, 8192, 512, 256, nullptr);
        hgemm_kernel<64, 64, false, false, false><<<dim3(128, 4), 256, 0, stream>>>(
            S1h, Wff216 + (size_t)l * 131072, tr_ff_b2 + l * 256,
            CF32, 8192, 256, 512, nullptr);
        add_ln_kernel<<<2048, 256, 0, stream>>>(X, CF32, tr_ln2_g + l * 256,
                                                tr_ln2_b + l * 256, X16);
    }

    // ---- pointer decode ----
    hgemm_kernel<64, 64, false, false, false><<<dim3(128, 4), 256, 0, stream>>>(
        X16, WpW16, ptr_b, EPROJ, 8192, 256, 256, nullptr);
    hgemm_kernel<64, 128, false, true, true><<<dim3(128, 8), 256, 0, stream>>>(
        X16, Wih16, PB, S1h, 8192, 1024, 256, target);
    lstm_kernel<<<32, 512, 0, stream>>>(S1h, (const uint4*)WBf, HALL16);
    hgemm_kernel<64, 64, false, false, false><<<dim3(128, 4), 256, 0, stream>>>(
        HALL16, WpW16, ptr_b, CF32, 8192, 256, 256, nullptr);
    pointer_kernel<<<dim3(4, 4, 32), 512, 0, stream>>>(CF32, EPROJ, ptr_v,
                                                       (float*)d_out);
}

// Round 10
// 1055.774 us; speedup vs baseline: 1.0061x; 1.0061x over previous
//
#include <hip/hip_runtime.h>
#include <cstddef>

#define DEV __device__ __forceinline__

DEV float fexp2(float x) { return __builtin_amdgcn_exp2f(x); }
DEV float frcp(float x)  { return __builtin_amdgcn_rcpf(x); }
DEV float fsigm(float x) { return frcp(1.0f + fexp2(-1.44269504f * x)); }
DEV float ftanh_(float x){ return 1.0f - 2.0f * frcp(1.0f + fexp2(2.88539008f * x)); }

typedef _Float16 h2t __attribute__((ext_vector_type(2)));
typedef _Float16 v8h __attribute__((ext_vector_type(8)));
typedef float v4f __attribute__((ext_vector_type(4)));
union U32H2 { unsigned int u; h2t h; };
DEV h2t u2h(unsigned int u) { U32H2 x; x.u = u; return x.h; }

// ---------------------------------------------------------------------------
// f16 MFMA GEMM: C[M,N] = A[M,K] @ W[N,K]^T + bias; A,W f16 row-major.
// BM in {64,128}, BK=32, 256 threads (4 waves, 2x2), wave tile (BM/2)x(BN/2).
// GATHER: A row r=(b,t) reads row target[b,t-1] of A (zeros for t=0).
// ---------------------------------------------------------------------------
template <int BM, int BN, bool RELU, bool OUTF16, bool GATHER>
__global__ __launch_bounds__(256) void hgemm_kernel(
    const _Float16* __restrict__ A, const _Float16* __restrict__ W,
    const float* __restrict__ bias1, void* __restrict__ Cout,
    int M, int N, int K, const int* __restrict__ target)
{
    constexpr int MT = BM / 32;
    constexpr int NT = BN / 32;
    constexpr int RA = BM / 64;
    constexpr int RB = BN / 64;
    __shared__ _Float16 As[BM * 32];
    __shared__ _Float16 Bs[BN * 32];

    const int tid = threadIdx.x;
    const int lane = tid & 63;
    const int lm = lane & 15, lq = lane >> 4;
    const int wrow = ((tid >> 6) & 1) * (BM / 2);
    const int wcol = (tid >> 7) * (BN / 2);
    const int m0 = blockIdx.x * BM, n0 = blockIdx.y * BN;
    const _Float16* Wb = W + (size_t)n0 * K;

    v4f acc[MT][NT];
#pragma unroll
    for (int i = 0; i < MT; ++i)
#pragma unroll
        for (int j = 0; j < NT; ++j) acc[i][j] = (v4f){0.f, 0.f, 0.f, 0.f};

    const int rowS = tid >> 2, qS = tid & 3;

    size_t arow[RA]; bool az[RA];
#pragma unroll
    for (int r = 0; r < RA; ++r) {
        int row = m0 + rowS + 64 * r;
        if (GATHER) {
            int b = row >> 8, t = row & 255;
            if (t == 0) { az[r] = true; arow[r] = 0; }
            else { az[r] = false;
                   arow[r] = (size_t)((b << 8) + target[(b << 8) + t - 1]); }
        } else { az[r] = false; arow[r] = (size_t)row; }
    }
    const uint4 z4 = {0u, 0u, 0u, 0u};

    uint4 ra[RA], rb[RB];
#pragma unroll
    for (int r = 0; r < RA; ++r)
        ra[r] = az[r] ? z4 : *(const uint4*)(A + arow[r] * K + qS * 8);
#pragma unroll
    for (int r = 0; r < RB; ++r)
        rb[r] = *(const uint4*)(Wb + (size_t)(rowS + 64 * r) * K + qS * 8);

    for (int k0 = 0; k0 < K; k0 += 32) {
        __syncthreads();
#pragma unroll
        for (int r = 0; r < RA; ++r)
            *(uint4*)(As + (size_t)(tid + 256 * r) * 8) = ra[r];
#pragma unroll
        for (int r = 0; r < RB; ++r)
            *(uint4*)(Bs + (size_t)(tid + 256 * r) * 8) = rb[r];
        __syncthreads();
        int kn = k0 + 32;
        if (kn < K) {
#pragma unroll
            for (int r = 0; r < RA; ++r)
                ra[r] = az[r] ? z4 : *(const uint4*)(A + arow[r] * K + kn + qS * 8);
#pragma unroll
            for (int r = 0; r < RB; ++r)
                rb[r] = *(const uint4*)(Wb + (size_t)(rowS + 64 * r) * K + kn + qS * 8);
        }
        v8h af[MT], bf[NT];
#pragma unroll
        for (int i = 0; i < MT; ++i)
            af[i] = *(const v8h*)(As + (size_t)(wrow + i * 16 + lm) * 32 + lq * 8);
#pragma unroll
        for (int j = 0; j < NT; ++j)
            bf[j] = *(const v8h*)(Bs + (size_t)(wcol + j * 16 + lm) * 32 + lq * 8);
#pragma unroll
        for (int i = 0; i < MT; ++i)
#pragma unroll
            for (int j = 0; j < NT; ++j)
                acc[i][j] = __builtin_amdgcn_mfma_f32_16x16x32_f16(
                    af[i], bf[j], acc[i][j], 0, 0, 0);
    }

#pragma unroll
    for (int j = 0; j < NT; ++j) {
        int col = n0 + wcol + j * 16 + lm;
        float bv = bias1[col];
#pragma unroll
        for (int i = 0; i < MT; ++i) {
            int rbase = m0 + wrow + i * 16 + lq * 4;
#pragma unroll
            for (int rg = 0; rg < 4; ++rg) {
                float vv = acc[i][j][rg] + bv;
                if (RELU) vv = fmaxf(vv, 0.f);
                if (OUTF16)
                    ((_Float16*)Cout)[(size_t)(rbase + rg) * N + col] = (_Float16)vv;
                else
                    ((float*)Cout)[(size_t)(rbase + rg) * N + col] = vv;
            }
        }
    }
}

// ---------------------------------------------------------------------------
// Fused weight conversion. Wih dest rows gate-interleaved: dest row
// j*4+g = src row g*256+j.
// ---------------------------------------------------------------------------
__global__ __launch_bounds__(256) void cvt_all_kernel(
    const float* __restrict__ s0, const float* __restrict__ s1,
    const float* __restrict__ s2, const float* __restrict__ s3,
    const float* __restrict__ s4, const float* __restrict__ s5,
    _Float16* __restrict__ dst)
{
    int i = blockIdx.x * 256 + threadIdx.x;
    if (i >= 1900544) return;
    float val;
    if (i < 589824)       val = s0[i];
    else if (i < 786432)  val = s1[i - 589824];
    else if (i < 1179648) val = s2[i - 786432];
    else if (i < 1572864) val = s3[i - 1179648];
    else if (i < 1835008) {
        int idx = i - 1572864;
        int rp = idx >> 8, k = idx & 255;
        int j = rp >> 2, g = rp & 3;
        val = s4[(g * 256 + j) * 256 + k];
    }
    else                  val = s5[i - 1835008];
    dst[i] = (_Float16)val;
}

// ---------------------------------------------------------------------------
__global__ __launch_bounds__(64) void bin_enc_kernel(
    const float* __restrict__ bin_info, const float* __restrict__ W1,
    const float* __restrict__ b1, const float* __restrict__ W2,
    const float* __restrict__ b2, float* __restrict__ BBo)
{
    int b = blockIdx.x, d = threadIdx.x;
    __shared__ float h1[64];
    float x0 = bin_info[b * 2], x1 = bin_info[b * 2 + 1];
    h1[d] = fmaxf(W1[d * 2] * x0 + W1[d * 2 + 1] * x1 + b1[d], 0.f);
    __syncthreads();
    float acc = b2[d];
#pragma unroll 4
    for (int e = 0; e < 64; ++e) acc += W2[d * 64 + e] * h1[e];
    BBo[b * 64 + d] = acc;
}

// ---------------------------------------------------------------------------
__global__ __launch_bounds__(128) void part_enc_kernel(
    const float* __restrict__ parts, const float* __restrict__ W1,
    const float* __restrict__ b1, const float* __restrict__ W2,
    const float* __restrict__ b2, const float* __restrict__ BBi,
    const float* __restrict__ pos_emb, float* __restrict__ X,
    _Float16* __restrict__ X16)
{
    __shared__ float W2s[128][129];
    __shared__ float h1[128];
    __shared__ float pin[16];
    int tid = threadIdx.x;
    int b = blockIdx.x >> 3, s0 = (blockIdx.x & 7) * 32;
    for (int l = 0; l < 128; ++l) W2s[l][tid] = W2[l * 128 + tid];
    float w1r[16];
#pragma unroll
    for (int k = 0; k < 16; ++k) w1r[k] = W1[tid * 16 + k];
    float bias1v = b1[tid], bias2v = b2[tid];
    for (int si = 0; si < 32; ++si) {
        int s = s0 + si;
        size_t row = (size_t)b * 256 + s;
        if (tid < 16) pin[tid] = parts[row * 16 + tid];
        __syncthreads();
        float h = bias1v;
#pragma unroll
        for (int k = 0; k < 16; ++k) h += w1r[k] * pin[k];
        h1[tid] = fmaxf(h, 0.f);
        __syncthreads();
        float acc = bias2v;
#pragma unroll 4
        for (int e = 0; e < 128; ++e) acc += W2s[tid][e] * h1[e];
        X[row * 256 + tid] = acc;
        X16[row * 256 + tid] = (_Float16)acc;
        if (tid < 64) {
            float bbv = BBi[b * 64 + tid];
            float pev = pos_emb[s * 64 + tid];
            X[row * 256 + 128 + tid] = bbv;
            X[row * 256 + 192 + tid] = pev;
            X16[row * 256 + 128 + tid] = (_Float16)bbv;
            X16[row * 256 + 192 + tid] = (_Float16)pev;
        }
        __syncthreads();
    }
}

// ---------------------------------------------------------------------------
// MFMA attention: one block per (b,h), 256 threads (4 waves).
// ---------------------------------------------------------------------------
__global__ __launch_bounds__(256) void attn_mfma_kernel(
    const _Float16* __restrict__ QKV, _Float16* __restrict__ O16)
{
    int bh = blockIdx.x;
    int b = bh >> 3, h = bh & 7;
    const int tid = threadIdx.x;
    const int w = tid >> 6;
    const int lane = tid & 63;
    const int lm = lane & 15, lq = lane >> 4;
    const float c_se = 0.17677669529663687f * 1.44269504f;

    __shared__ _Float16 Ks[4][256][8];
    __shared__ _Float16 Vt[32][264];
    __shared__ _Float16 Ps[4][16][264];

    const _Float16* qkvb = QKV + (size_t)(b * 256) * 768 + h * 32;
    {
        int s = tid;
        const _Float16* kr = qkvb + (size_t)s * 768 + 256;
#pragma unroll
        for (int c = 0; c < 4; ++c)
            *(uint4*)&Ks[c][s][0] = *(const uint4*)(kr + c * 8);
        const _Float16* vr = qkvb + (size_t)s * 768 + 512;
        _Float16 vtmp[32];
        *(uint4*)&vtmp[0]  = *(const uint4*)(vr);
        *(uint4*)&vtmp[8]  = *(const uint4*)(vr + 8);
        *(uint4*)&vtmp[16] = *(const uint4*)(vr + 16);
        *(uint4*)&vtmp[24] = *(const uint4*)(vr + 24);
#pragma unroll
        for (int d = 0; d < 32; ++d) Vt[d][s] = vtmp[d];
    }
    __syncthreads();

#pragma unroll 1
    for (int st = 0; st < 4; ++st) {
        int rt = w * 4 + st;
        v8h qf = *(const v8h*)(QKV + (size_t)(b * 256 + rt * 16 + lm) * 768
                               + h * 32 + lq * 8);
        v4f acc[16];
#pragma unroll
        for (int ct = 0; ct < 16; ++ct) {
            v8h kf = *(const v8h*)&Ks[lq][ct * 16 + lm][0];
            acc[ct] = __builtin_amdgcn_mfma_f32_16x16x32_f16(
                qf, kf, (v4f){0.f, 0.f, 0.f, 0.f}, 0, 0, 0);
        }
        float sminv[4];
#pragma unroll
        for (int r = 0; r < 4; ++r) {
            float m = acc[0][r];
#pragma unroll
            for (int ct = 1; ct < 16; ++ct) m = fmaxf(m, acc[ct][r]);
#pragma unroll
            for (int msk = 1; msk < 16; msk <<= 1)
                m = fmaxf(m, __shfl_xor(m, msk));
            float ssum = 0.f;
#pragma unroll
            for (int ct = 0; ct < 16; ++ct) {
                float e = fexp2((acc[ct][r] - m) * c_se);
                acc[ct][r] = e;
                ssum += e;
            }
#pragma unroll
            for (int msk = 1; msk < 16; msk <<= 1)
                ssum += __shfl_xor(ssum, msk);
            sminv[r] = frcp(ssum);
        }
#pragma unroll
        for (int ct = 0; ct < 16; ++ct)
#pragma unroll
            for (int r = 0; r < 4; ++r)
                Ps[w][lq * 4 + r][ct * 16 + lm] =
                    (_Float16)(acc[ct][r] * sminv[r]);
#pragma unroll
        for (int dt = 0; dt < 2; ++dt) {
            v4f o = (v4f){0.f, 0.f, 0.f, 0.f};
#pragma unroll
            for (int jc = 0; jc < 8; ++jc) {
                v8h pf = *(const v8h*)&Ps[w][lm][jc * 32 + lq * 8];
                v8h vf = *(const v8h*)&Vt[dt * 16 + lm][jc * 32 + lq * 8];
                o = __builtin_amdgcn_mfma_f32_16x16x32_f16(pf, vf, o, 0, 0, 0);
            }
#pragma unroll
            for (int r = 0; r < 4; ++r)
                O16[(size_t)(b * 256 + rt * 16 + lq * 4 + r) * 256
                    + h * 32 + dt * 16 + lm] = (_Float16)o[r];
        }
    }
}

// ---------------------------------------------------------------------------
// Residual add + LayerNorm, wave-per-row. grid = rows/4.
// ---------------------------------------------------------------------------
__global__ __launch_bounds__(256) void add_ln_kernel(
    float* __restrict__ X, const float* __restrict__ R,
    const float* __restrict__ g, const float* __restrict__ beta,
    _Float16* __restrict__ X16)
{
    int row = blockIdx.x * 4 + (threadIdx.x >> 6);
    int lane = threadIdx.x & 63;
    size_t base = (size_t)row * 256 + lane * 4;
    float4 xv = *(const float4*)&X[base];
    float4 rv = *(const float4*)&R[base];
    float y0 = xv.x + rv.x, y1 = xv.y + rv.y;
    float y2 = xv.z + rv.z, y3 = xv.w + rv.w;
    float s = y0 + y1 + y2 + y3;
    float s2 = y0 * y0 + y1 * y1 + y2 * y2 + y3 * y3;
#pragma unroll
    for (int m = 1; m < 64; m <<= 1) {
        s += __shfl_xor(s, m);
        s2 += __shfl_xor(s2, m);
    }
    float mean = s * (1.f / 256.f);
    float var = s2 * (1.f / 256.f) - mean * mean;
    float inv = rsqrtf(var + 1e-5f);
    float4 gv = *(const float4*)&g[lane * 4];
    float4 bv = *(const float4*)&beta[lane * 4];
    float o0 = (y0 - mean) * inv * gv.x + bv.x;
    float o1 = (y1 - mean) * inv * gv.y + bv.y;
    float o2 = (y2 - mean) * inv * gv.z + bv.z;
    float o3 = (y3 - mean) * inv * gv.w + bv.w;
    *(float4*)&X[base] = make_float4(o0, o1, o2, o3);
    U32H2 a, c;
    a.h = h2t{(_Float16)o0, (_Float16)o1};
    c.h = h2t{(_Float16)o2, (_Float16)o3};
    uint2 u; u.x = a.u; u.y = c.u;
    *(uint2*)(X16 + base) = u;
}

// ---------------------------------------------------------------------------
// Whh fp32 [1024,256] -> f16x2 blob; split: LDS 8 words (c<2), regs 44
// (2<=c<13), stream 12 (13<=c<16). Also builds permuted lstm bias PB.
// ---------------------------------------------------------------------------
__global__ __launch_bounds__(256) void wcvt2_kernel(
    const float* __restrict__ Whh, unsigned int* __restrict__ WB,
    const float* __restrict__ bih, const float* __restrict__ bhh,
    float* __restrict__ PB)
{
    int idx = blockIdx.x * 256 + threadIdx.x;  // 0..131071
    if (idx < 1024) {
        int j = idx >> 2, g = idx & 3;
        PB[idx] = bih[g * 256 + j] + bhh[g * 256 + j];
    }
    int l = idx & 3;
    int gt = idx >> 2;
    int tid = gt & 511;
    int q = gt >> 9;                            // 0..63
    int i, c;
    if (q < 8)       { i = q >> 1; c = q & 1; }
    else if (q < 52) { int qq = q - 8; i = qq / 11; c = 2 + qq % 11; }
    else             { int qq = q - 52; c = 13 + (qq >> 2); i = qq & 3; }
    int r = ((tid & 255) << 2) + i;
    int k = ((tid >> 8) << 7) + (c << 3) + (l << 1);
    _Float16 lo = (_Float16)Whh[r * 256 + k];
    _Float16 hi = (_Float16)Whh[r * 256 + k + 1];
    U32H2 x; x.h = h2t{lo, hi};
    WB[idx] = x.u;
}

// ---------------------------------------------------------------------------
// LSTM recurrence: 1 block/batch, 512 threads. Weights: 64 KB LDS +
// reg slab + 96 KB/step L2 stream. g_in f16 gate-interleaved [t][j*4+g].
// ---------------------------------------------------------------------------
__global__ __launch_bounds__(512) void lstm_kernel(
    const _Float16* __restrict__ g_in, const uint4* __restrict__ WB4,
    _Float16* __restrict__ HALL16)
{
    const int b = blockIdx.x;
    const int tid = threadIdx.x;
    const int kh = tid >> 8, j4 = tid & 255;

    __shared__ uint4 WL4[4096];        // 64 KB
    __shared__ float gpart[2][1024];   // 8 KB
    __shared__ uint4 h2v[32];          // 512 B
    unsigned int* h2_s = (unsigned int*)h2v;

#pragma unroll
    for (int g = 0; g < 8; ++g) WL4[g * 512 + tid] = WB4[g * 512 + tid];
    uint4 wr[44];
#pragma unroll
    for (int q = 0; q < 44; ++q) wr[q] = WB4[(8 + q) * 512 + tid];
    if (tid < 128) h2_s[tid] = 0u;

    const _Float16* ginb = g_in + (size_t)b * 256 * 1024;
    uint2 gi = make_uint2(0u, 0u);
    if (tid < 256) gi = *(const uint2*)(ginb + tid * 4);
    float c_state = 0.f;
    const uint4* SW4 = WB4 + 52 * 512;
    __syncthreads();

    for (int t = 0; t < 256; ++t) {
        uint4 sw[12];
#pragma unroll
        for (int q = 0; q < 4; ++q) sw[q] = SW4[q * 512 + tid];

        float acc[4] = {0.f, 0.f, 0.f, 0.f};
#pragma unroll
        for (int c = 0; c < 16; ++c) {
            if (c == 2) {
#pragma unroll
                for (int q = 4; q < 8; ++q) sw[q] = SW4[q * 512 + tid];
            }
            if (c == 6) {
#pragma unroll
                for (int q = 8; q < 12; ++q) sw[q] = SW4[q * 512 + tid];
            }
            uint4 h4 = h2v[(kh << 4) + c];
            h2t hx = u2h(h4.x), hy = u2h(h4.y), hz = u2h(h4.z), hw = u2h(h4.w);
#pragma unroll
            for (int i = 0; i < 4; ++i) {
                uint4 w = (c < 2)  ? WL4[((i << 1) + c) * 512 + tid]
                        : (c < 13) ? wr[i * 11 + (c - 2)]
                                   : sw[((c - 13) << 2) + i];
                acc[i] = __builtin_amdgcn_fdot2(u2h(w.x), hx, acc[i], false);
                acc[i] = __builtin_amdgcn_fdot2(u2h(w.y), hy, acc[i], false);
                acc[i] = __builtin_amdgcn_fdot2(u2h(w.z), hz, acc[i], false);
                acc[i] = __builtin_amdgcn_fdot2(u2h(w.w), hw, acc[i], false);
            }
        }
        *(float4*)&gpart[kh][j4 << 2] = make_float4(acc[0], acc[1], acc[2], acc[3]);
        __syncthreads();

        if (tid < 256) {
            int j = tid;
            h2t p0 = u2h(gi.x), p1 = u2h(gi.y);
            float ig = (float)p0.x + gpart[0][j]       + gpart[1][j];
            float fg = (float)p0.y + gpart[0][j + 256] + gpart[1][j + 256];
            float gg = (float)p1.x + gpart[0][j + 512] + gpart[1][j + 512];
            float og = (float)p1.y + gpart[0][j + 768] + gpart[1][j + 768];
            c_state = fsigm(fg) * c_state + fsigm(ig) * ftanh_(gg);
            float h = fsigm(og) * ftanh_(c_state);
            HALL16[((size_t)(b * 256 + t)) * 256 + j] = (_Float16)h;
            U32H2 hxp; hxp.h = h2t{(_Float16)h, (_Float16)0.f};
            unsigned int hu = hxp.u & 0xffffu;
            unsigned int other = (unsigned int)__shfl_xor((int)hu, 1);
            if ((j & 1) == 0) h2_s[j >> 1] = hu | (other << 16);
            int tn = (t < 255) ? (t + 1) : 255;
            gi = *(const uint2*)(ginb + (size_t)tn * 1024 + j * 4);
        }
        __syncthreads();
    }
}

// ---------------------------------------------------------------------------
// Pointer logits (R7 version): out = vsum - 2*sum_d v_d/(1+exp2(2.88539*(hp+ep)))
// 16x16 tile per block, 256 threads, one output each.
// ---------------------------------------------------------------------------
__global__ __launch_bounds__(256) void pointer_kernel(
    const float* __restrict__ HP, const float* __restrict__ EP,
    const float* __restrict__ v, float* __restrict__ out)
{
    int b = blockIdx.z, tt = blockIdx.y, it = blockIdx.x;
    __shared__ float hp_s[16][260];
    __shared__ float ep_s[16][260];
    __shared__ float v_s[256];
    __shared__ float red[4];
    int tid = threadIdx.x;
    const float cs = 2.88539008f;
    const float* hpb = HP + ((size_t)b * 256 + tt * 16) * 256;
    const float* epb = EP + ((size_t)b * 256 + it * 16) * 256;
#pragma unroll
    for (int l = 0; l < 4; ++l) {
        int idx = tid + l * 256;
        int r = idx >> 6, c4 = idx & 63;
        float4 hv = *(const float4*)(hpb + r * 256 + c4 * 4);
        hv.x *= cs; hv.y *= cs; hv.z *= cs; hv.w *= cs;
        *(float4*)&hp_s[r][c4 * 4] = hv;
        float4 ev = *(const float4*)(epb + r * 256 + c4 * 4);
        ev.x *= cs; ev.y *= cs; ev.z *= cs; ev.w *= cs;
        *(float4*)&ep_s[r][c4 * 4] = ev;
    }
    float vv = v[tid];
    v_s[tid] = vv;
    float vp = vv;
#pragma unroll
    for (int m = 1; m < 64; m <<= 1) vp += __shfl_xor(vp, m);
    if ((tid & 63) == 0) red[tid >> 6] = vp;
    __syncthreads();
    float vsum = red[0] + red[1] + red[2] + red[3];
    int tl = tid >> 4, il = tid & 15;
    float acc = 0.f;
#pragma unroll 4
    for (int d = 0; d < 256; ++d) {
        float sval = hp_s[tl][d] + ep_s[il][d];
        float r = frcp(1.0f + fexp2(sval));
        acc = fmaf(v_s[d], r, acc);
    }
    out[((size_t)b * 256 + tt * 16 + tl) * 256 + it * 16 + il] =
        vsum - 2.0f * acc;
}

// ---------------------------------------------------------------------------
extern "C" void kernel_launch(void* const* d_in, const int* in_sizes, int n_in,
                              void* d_out, int out_size, void* d_ws, size_t ws_size,
                              hipStream_t stream)
{
    const float* parts    = (const float*)d_in[0];
    const float* bin_info = (const float*)d_in[1];
    const int*   target   = (const int*)d_in[2];
    const float* pe_W1 = (const float*)d_in[3];
    const float* pe_b1 = (const float*)d_in[4];
    const float* pe_W2 = (const float*)d_in[5];
    const float* pe_b2 = (const float*)d_in[6];
    const float* be_W1 = (const float*)d_in[7];
    const float* be_b1 = (const float*)d_in[8];
    const float* be_W2 = (const float*)d_in[9];
    const float* be_b2 = (const float*)d_in[10];
    const float* pos_emb = (const float*)d_in[11];
    const float* tr_Wqkv = (const float*)d_in[12];
    const float* tr_bqkv = (const float*)d_in[13];
    const float* tr_Wo   = (const float*)d_in[14];
    const float* tr_bo   = (const float*)d_in[15];
    const float* tr_ln1_g = (const float*)d_in[16];
    const float* tr_ln1_b = (const float*)d_in[17];
    const float* tr_ff_W1 = (const float*)d_in[18];
    const float* tr_ff_b1 = (const float*)d_in[19];
    const float* tr_ff_W2 = (const float*)d_in[20];
    const float* tr_ff_b2 = (const float*)d_in[21];
    const float* tr_ln2_g = (const float*)d_in[22];
    const float* tr_ln2_b = (const float*)d_in[23];
    const float* lstm_Wih = (const float*)d_in[24];
    const float* lstm_Whh = (const float*)d_in[25];
    const float* lstm_bih = (const float*)d_in[26];
    const float* lstm_bhh = (const float*)d_in[27];
    const float* ptr_W = (const float*)d_in[28];
    const float* ptr_b = (const float*)d_in[29];
    const float* ptr_v = (const float*)d_in[30];

    // ---- workspace layout (floats) ----
    float* ws = (float*)d_ws;
    float* X     = ws;                        // 2,097,152
    float* S1    = X + 2097152;               // 8,388,608 (qkv/ff1/g_in f16)
    float* CF32  = S1 + 8388608;              // 2,097,152
    float* EPROJ = CF32 + 2097152;            // 2,097,152
    float* X16f  = EPROJ + 2097152;           // 1,048,576
    float* S2f   = X16f + 1048576;            // 1,048,576
    float* W16f  = S2f + 1048576;             // 1,048,576
    float* WBf   = W16f + 1048576;            // 131,072
    float* BBuf  = WBf + 131072;              // 2,048
    float* PB    = BBuf + 2048;               // 1,024

    _Float16* X16    = (_Float16*)X16f;
    _Float16* S2h    = (_Float16*)S2f;
    _Float16* HALL16 = S2h;
    _Float16* S1h    = (_Float16*)S1;
    _Float16* W16    = (_Float16*)W16f;
    _Float16* Wqkv16 = W16;                   // 589,824
    _Float16* Wo16   = Wqkv16 + 589824;       // 196,608
    _Float16* Wff116 = Wo16 + 196608;         // 393,216
    _Float16* Wff216 = Wff116 + 393216;       // 393,216
    _Float16* Wih16  = Wff216 + 393216;       // 262,144 (gate-interleaved rows)
    _Float16* WpW16  = Wih16 + 262144;        // 65,536

    // ---- one-time weight conversions ----
    cvt_all_kernel<<<7424, 256, 0, stream>>>(tr_Wqkv, tr_Wo, tr_ff_W1, tr_ff_W2,
                                             lstm_Wih, ptr_W, W16);
    wcvt2_kernel<<<512, 256, 0, stream>>>(lstm_Whh, (unsigned int*)WBf,
                                          lstm_bih, lstm_bhh, PB);

    // ---- encoders ----
    bin_enc_kernel<<<32, 64, 0, stream>>>(bin_info, be_W1, be_b1, be_W2, be_b2, BBuf);
    part_enc_kernel<<<256, 128, 0, stream>>>(parts, pe_W1, pe_b1, pe_W2, pe_b2,
                                             BBuf, pos_emb, X, X16);

    // ---- transformer layers ----
    for (int l = 0; l < 3; ++l) {
        hgemm_kernel<64, 128, false, true, false><<<dim3(128, 6), 256, 0, stream>>>(
            X16, Wqkv16 + (size_t)l * 196608, tr_bqkv + l * 768,
            S1h, 8192, 768, 256, nullptr);
        attn_mfma_kernel<<<256, 256, 0, stream>>>(S1h, S2h);
        hgemm_kernel<64, 64, false, false, false><<<dim3(128, 4), 256, 0, stream>>>(
            S2h, Wo16 + (size_t)l * 65536, tr_bo + l * 256,
            CF32, 8192, 256, 256, nullptr);
        add_ln_kernel<<<2048, 256, 0, stream>>>(X, CF32, tr_ln1_g + l * 256,
                                                tr_ln1_b + l * 256, X16);
        hgemm_kernel<64, 128, true, true, false><<<dim3(128, 4), 256, 0, stream>>>(
            X16, Wff116 + (size_t)l * 131072, tr_ff_b1 + l * 512,
            S1h, 8192, 512, 256, nullptr);
        hgemm_kernel<64, 64, false, false, false><<<dim3(128, 4), 256, 0, stream>>>(
            S1h, Wff216 + (size_t)l * 131072, tr_ff_b2 + l * 256,
            CF32, 8192, 256, 512, nullptr);
        add_ln_kernel<<<2048, 256, 0, stream>>>(X, CF32, tr_ln2_g + l * 256,
                                                tr_ln2_b + l * 256, X16);
    }

    // ---- pointer decode ----
    hgemm_kernel<64, 64, false, false, false><<<dim3(128, 4), 256, 0, stream>>>(
        X16, WpW16, ptr_b, EPROJ, 8192, 256, 256, nullptr);
    hgemm_kernel<64, 128, false, true, true><<<dim3(128, 8), 256, 0, stream>>>(
        X16, Wih16, PB, S1h, 8192, 1024, 256, target);
    lstm_kernel<<<32, 512, 0, stream>>>(S1h, (const uint4*)WBf, HALL16);
    hgemm_kernel<64, 64, false, false, false><<<dim3(128, 4), 256, 0, stream>>>(
        HALL16, WpW16, ptr_b, CF32, 8192, 256, 256, nullptr);
    pointer_kernel<<<dim3(16, 16, 32), 256, 0, stream>>>(CF32, EPROJ, ptr_v,
                                                         (float*)d_out);
}

// Round 11
// 971.724 us; speedup vs baseline: 1.0932x; 1.0865x over previous
//
#include <hip/hip_runtime.h>
#include <cstddef>

#define DEV __device__ __forceinline__

DEV float fexp2(float x) { return __builtin_amdgcn_exp2f(x); }
DEV float frcp(float x)  { return __builtin_amdgcn_rcpf(x); }
DEV float fsigm(float x) { return frcp(1.0f + fexp2(-1.44269504f * x)); }
DEV float ftanh_(float x){ return 1.0f - 2.0f * frcp(1.0f + fexp2(2.88539008f * x)); }

typedef _Float16 h2t __attribute__((ext_vector_type(2)));
typedef _Float16 v8h __attribute__((ext_vector_type(8)));
typedef float v4f __attribute__((ext_vector_type(4)));
union U32H2 { unsigned int u; h2t h; };
DEV h2t u2h(unsigned int u) { U32H2 x; x.u = u; return x.h; }

// ---------------------------------------------------------------------------
// f16 MFMA GEMM (R7 version, verbatim): C[M,N] = A[M,K] @ W[N,K]^T + bias.
// BM in {64,128}, BK=32, 256 threads (4 waves, 2x2), wave tile (BM/2)x(BN/2).
// ---------------------------------------------------------------------------
template <int BM, int BN, bool RELU, bool OUTF16>
__global__ __launch_bounds__(256) void hgemm_kernel(
    const _Float16* __restrict__ A, const _Float16* __restrict__ W,
    const float* __restrict__ bias1, const float* __restrict__ bias2,
    void* __restrict__ Cout, int M, int N, int K)
{
    constexpr int MT = BM / 32;
    constexpr int NT = BN / 32;
    constexpr int RA = BM / 64;
    constexpr int RB = BN / 64;
    __shared__ _Float16 As[BM * 32];
    __shared__ _Float16 Bs[BN * 32];

    const int tid = threadIdx.x;
    const int lane = tid & 63;
    const int lm = lane & 15, lq = lane >> 4;
    const int wrow = ((tid >> 6) & 1) * (BM / 2);
    const int wcol = (tid >> 7) * (BN / 2);
    const int m0 = blockIdx.x * BM, n0 = blockIdx.y * BN;
    const _Float16* Ab = A + (size_t)m0 * K;
    const _Float16* Wb = W + (size_t)n0 * K;

    v4f acc[MT][NT];
#pragma unroll
    for (int i = 0; i < MT; ++i)
#pragma unroll
        for (int j = 0; j < NT; ++j) acc[i][j] = (v4f){0.f, 0.f, 0.f, 0.f};

    const int rowS = tid >> 2, qS = tid & 3;

    uint4 ra[RA], rb[RB];
#pragma unroll
    for (int r = 0; r < RA; ++r)
        ra[r] = *(const uint4*)(Ab + (size_t)(rowS + 64 * r) * K + qS * 8);
#pragma unroll
    for (int r = 0; r < RB; ++r)
        rb[r] = *(const uint4*)(Wb + (size_t)(rowS + 64 * r) * K + qS * 8);

    for (int k0 = 0; k0 < K; k0 += 32) {
        __syncthreads();
#pragma unroll
        for (int r = 0; r < RA; ++r)
            *(uint4*)(As + (size_t)(tid + 256 * r) * 8) = ra[r];
#pragma unroll
        for (int r = 0; r < RB; ++r)
            *(uint4*)(Bs + (size_t)(tid + 256 * r) * 8) = rb[r];
        __syncthreads();
        int kn = k0 + 32;
        if (kn < K) {
#pragma unroll
            for (int r = 0; r < RA; ++r)
                ra[r] = *(const uint4*)(Ab + (size_t)(rowS + 64 * r) * K + kn + qS * 8);
#pragma unroll
            for (int r = 0; r < RB; ++r)
                rb[r] = *(const uint4*)(Wb + (size_t)(rowS + 64 * r) * K + kn + qS * 8);
        }
        v8h af[MT], bf[NT];
#pragma unroll
        for (int i = 0; i < MT; ++i)
            af[i] = *(const v8h*)(As + (size_t)(wrow + i * 16 + lm) * 32 + lq * 8);
#pragma unroll
        for (int j = 0; j < NT; ++j)
            bf[j] = *(const v8h*)(Bs + (size_t)(wcol + j * 16 + lm) * 32 + lq * 8);
#pragma unroll
        for (int i = 0; i < MT; ++i)
#pragma unroll
            for (int j = 0; j < NT; ++j)
                acc[i][j] = __builtin_amdgcn_mfma_f32_16x16x32_f16(
                    af[i], bf[j], acc[i][j], 0, 0, 0);
    }

#pragma unroll
    for (int j = 0; j < NT; ++j) {
        int col = n0 + wcol + j * 16 + lm;
        float bv = bias1[col];
        if (bias2) bv += bias2[col];
#pragma unroll
        for (int i = 0; i < MT; ++i) {
            int rbase = m0 + wrow + i * 16 + lq * 4;
#pragma unroll
            for (int rg = 0; rg < 4; ++rg) {
                float vv = acc[i][j][rg] + bv;
                if (RELU) vv = fmaxf(vv, 0.f);
                if (OUTF16)
                    ((_Float16*)Cout)[(size_t)(rbase + rg) * N + col] = (_Float16)vv;
                else
                    ((float*)Cout)[(size_t)(rbase + rg) * N + col] = vv;
            }
        }
    }
}

// ---------------------------------------------------------------------------
// Fused weight conversion. Wih dest rows gate-interleaved: dest row
// j*4+g = src row g*256+j.
// ---------------------------------------------------------------------------
__global__ __launch_bounds__(256) void cvt_all_kernel(
    const float* __restrict__ s0, const float* __restrict__ s1,
    const float* __restrict__ s2, const float* __restrict__ s3,
    const float* __restrict__ s4, const float* __restrict__ s5,
    _Float16* __restrict__ dst)
{
    int i = blockIdx.x * 256 + threadIdx.x;
    if (i >= 1900544) return;
    float val;
    if (i < 589824)       val = s0[i];
    else if (i < 786432)  val = s1[i - 589824];
    else if (i < 1179648) val = s2[i - 786432];
    else if (i < 1572864) val = s3[i - 1179648];
    else if (i < 1835008) {
        int idx = i - 1572864;
        int rp = idx >> 8, k = idx & 255;
        int j = rp >> 2, g = rp & 3;
        val = s4[(g * 256 + j) * 256 + k];
    }
    else                  val = s5[i - 1835008];
    dst[i] = (_Float16)val;
}

// ---------------------------------------------------------------------------
__global__ __launch_bounds__(64) void bin_enc_kernel(
    const float* __restrict__ bin_info, const float* __restrict__ W1,
    const float* __restrict__ b1, const float* __restrict__ W2,
    const float* __restrict__ b2, float* __restrict__ BBo)
{
    int b = blockIdx.x, d = threadIdx.x;
    __shared__ float h1[64];
    float x0 = bin_info[b * 2], x1 = bin_info[b * 2 + 1];
    h1[d] = fmaxf(W1[d * 2] * x0 + W1[d * 2 + 1] * x1 + b1[d], 0.f);
    __syncthreads();
    float acc = b2[d];
#pragma unroll 4
    for (int e = 0; e < 64; ++e) acc += W2[d * 64 + e] * h1[e];
    BBo[b * 64 + d] = acc;
}

// ---------------------------------------------------------------------------
__global__ __launch_bounds__(128) void part_enc_kernel(
    const float* __restrict__ parts, const float* __restrict__ W1,
    const float* __restrict__ b1, const float* __restrict__ W2,
    const float* __restrict__ b2, const float* __restrict__ BBi,
    const float* __restrict__ pos_emb, float* __restrict__ X,
    _Float16* __restrict__ X16)
{
    __shared__ float W2s[128][129];
    __shared__ float h1[128];
    __shared__ float pin[16];
    int tid = threadIdx.x;
    int b = blockIdx.x >> 3, s0 = (blockIdx.x & 7) * 32;
    for (int l = 0; l < 128; ++l) W2s[l][tid] = W2[l * 128 + tid];
    float w1r[16];
#pragma unroll
    for (int k = 0; k < 16; ++k) w1r[k] = W1[tid * 16 + k];
    float bias1v = b1[tid], bias2v = b2[tid];
    for (int si = 0; si < 32; ++si) {
        int s = s0 + si;
        size_t row = (size_t)b * 256 + s;
        if (tid < 16) pin[tid] = parts[row * 16 + tid];
        __syncthreads();
        float h = bias1v;
#pragma unroll
        for (int k = 0; k < 16; ++k) h += w1r[k] * pin[k];
        h1[tid] = fmaxf(h, 0.f);
        __syncthreads();
        float acc = bias2v;
#pragma unroll 4
        for (int e = 0; e < 128; ++e) acc += W2s[tid][e] * h1[e];
        X[row * 256 + tid] = acc;
        X16[row * 256 + tid] = (_Float16)acc;
        if (tid < 64) {
            float bbv = BBi[b * 64 + tid];
            float pev = pos_emb[s * 64 + tid];
            X[row * 256 + 128 + tid] = bbv;
            X[row * 256 + 192 + tid] = pev;
            X16[row * 256 + 128 + tid] = (_Float16)bbv;
            X16[row * 256 + 192 + tid] = (_Float16)pev;
        }
        __syncthreads();
    }
}

// ---------------------------------------------------------------------------
// MFMA attention: one block per (b,h), 256 threads (4 waves).
// ---------------------------------------------------------------------------
__global__ __launch_bounds__(256) void attn_mfma_kernel(
    const _Float16* __restrict__ QKV, _Float16* __restrict__ O16)
{
    int bh = blockIdx.x;
    int b = bh >> 3, h = bh & 7;
    const int tid = threadIdx.x;
    const int w = tid >> 6;
    const int lane = tid & 63;
    const int lm = lane & 15, lq = lane >> 4;
    const float c_se = 0.17677669529663687f * 1.44269504f;

    __shared__ _Float16 Ks[4][256][8];
    __shared__ _Float16 Vt[32][264];
    __shared__ _Float16 Ps[4][16][264];

    const _Float16* qkvb = QKV + (size_t)(b * 256) * 768 + h * 32;
    {
        int s = tid;
        const _Float16* kr = qkvb + (size_t)s * 768 + 256;
#pragma unroll
        for (int c = 0; c < 4; ++c)
            *(uint4*)&Ks[c][s][0] = *(const uint4*)(kr + c * 8);
        const _Float16* vr = qkvb + (size_t)s * 768 + 512;
        _Float16 vtmp[32];
        *(uint4*)&vtmp[0]  = *(const uint4*)(vr);
        *(uint4*)&vtmp[8]  = *(const uint4*)(vr + 8);
        *(uint4*)&vtmp[16] = *(const uint4*)(vr + 16);
        *(uint4*)&vtmp[24] = *(const uint4*)(vr + 24);
#pragma unroll
        for (int d = 0; d < 32; ++d) Vt[d][s] = vtmp[d];
    }
    __syncthreads();

#pragma unroll 1
    for (int st = 0; st < 4; ++st) {
        int rt = w * 4 + st;
        v8h qf = *(const v8h*)(QKV + (size_t)(b * 256 + rt * 16 + lm) * 768
                               + h * 32 + lq * 8);
        v4f acc[16];
#pragma unroll
        for (int ct = 0; ct < 16; ++ct) {
            v8h kf = *(const v8h*)&Ks[lq][ct * 16 + lm][0];
            acc[ct] = __builtin_amdgcn_mfma_f32_16x16x32_f16(
                qf, kf, (v4f){0.f, 0.f, 0.f, 0.f}, 0, 0, 0);
        }
        float sminv[4];
#pragma unroll
        for (int r = 0; r < 4; ++r) {
            float m = acc[0][r];
#pragma unroll
            for (int ct = 1; ct < 16; ++ct) m = fmaxf(m, acc[ct][r]);
#pragma unroll
            for (int msk = 1; msk < 16; msk <<= 1)
                m = fmaxf(m, __shfl_xor(m, msk));
            float ssum = 0.f;
#pragma unroll
            for (int ct = 0; ct < 16; ++ct) {
                float e = fexp2((acc[ct][r] - m) * c_se);
                acc[ct][r] = e;
                ssum += e;
            }
#pragma unroll
            for (int msk = 1; msk < 16; msk <<= 1)
                ssum += __shfl_xor(ssum, msk);
            sminv[r] = frcp(ssum);
        }
#pragma unroll
        for (int ct = 0; ct < 16; ++ct)
#pragma unroll
            for (int r = 0; r < 4; ++r)
                Ps[w][lq * 4 + r][ct * 16 + lm] =
                    (_Float16)(acc[ct][r] * sminv[r]);
#pragma unroll
        for (int dt = 0; dt < 2; ++dt) {
            v4f o = (v4f){0.f, 0.f, 0.f, 0.f};
#pragma unroll
            for (int jc = 0; jc < 8; ++jc) {
                v8h pf = *(const v8h*)&Ps[w][lm][jc * 32 + lq * 8];
                v8h vf = *(const v8h*)&Vt[dt * 16 + lm][jc * 32 + lq * 8];
                o = __builtin_amdgcn_mfma_f32_16x16x32_f16(pf, vf, o, 0, 0, 0);
            }
#pragma unroll
            for (int r = 0; r < 4; ++r)
                O16[(size_t)(b * 256 + rt * 16 + lq * 4 + r) * 256
                    + h * 32 + dt * 16 + lm] = (_Float16)o[r];
        }
    }
}

// ---------------------------------------------------------------------------
// Residual add + LayerNorm, wave-per-row. grid = rows/4.
// ---------------------------------------------------------------------------
__global__ __launch_bounds__(256) void add_ln_kernel(
    float* __restrict__ X, const float* __restrict__ R,
    const float* __restrict__ g, const float* __restrict__ beta,
    _Float16* __restrict__ X16)
{
    int row = blockIdx.x * 4 + (threadIdx.x >> 6);
    int lane = threadIdx.x & 63;
    size_t base = (size_t)row * 256 + lane * 4;
    float4 xv = *(const float4*)&X[base];
    float4 rv = *(const float4*)&R[base];
    float y0 = xv.x + rv.x, y1 = xv.y + rv.y;
    float y2 = xv.z + rv.z, y3 = xv.w + rv.w;
    float s = y0 + y1 + y2 + y3;
    float s2 = y0 * y0 + y1 * y1 + y2 * y2 + y3 * y3;
#pragma unroll
    for (int m = 1; m < 64; m <<= 1) {
        s += __shfl_xor(s, m);
        s2 += __shfl_xor(s2, m);
    }
    float mean = s * (1.f / 256.f);
    float var = s2 * (1.f / 256.f) - mean * mean;
    float inv = rsqrtf(var + 1e-5f);
    float4 gv = *(const float4*)&g[lane * 4];
    float4 bv = *(const float4*)&beta[lane * 4];
    float o0 = (y0 - mean) * inv * gv.x + bv.x;
    float o1 = (y1 - mean) * inv * gv.y + bv.y;
    float o2 = (y2 - mean) * inv * gv.z + bv.z;
    float o3 = (y3 - mean) * inv * gv.w + bv.w;
    *(float4*)&X[base] = make_float4(o0, o1, o2, o3);
    U32H2 a, c;
    a.h = h2t{(_Float16)o0, (_Float16)o1};
    c.h = h2t{(_Float16)o2, (_Float16)o3};
    uint2 u; u.x = a.u; u.y = c.u;
    *(uint2*)(X16 + base) = u;
}

// ---------------------------------------------------------------------------
__global__ __launch_bounds__(256) void gather_kernel(
    const float* __restrict__ X, const int* __restrict__ target,
    _Float16* __restrict__ Xg16)
{
    int row = blockIdx.x;
    int b = row >> 8, t = row & 255;
    int d = threadIdx.x;
    float val = 0.f;
    if (t > 0) {
        int src = target[b * 256 + t - 1];
        val = X[((size_t)b * 256 + src) * 256 + d];
    }
    Xg16[(size_t)row * 256 + d] = (_Float16)val;
}

// ---------------------------------------------------------------------------
// Whh fp32 [1024,256] -> f16x2 blob; NEW split: LDS 16 uint4-slots (c<4),
// regs 44 (4<=c<15), stream 4 (c=15). Also builds permuted lstm bias PB.
// ---------------------------------------------------------------------------
__global__ __launch_bounds__(256) void wcvt2_kernel(
    const float* __restrict__ Whh, unsigned int* __restrict__ WB,
    const float* __restrict__ bih, const float* __restrict__ bhh,
    float* __restrict__ PB)
{
    int idx = blockIdx.x * 256 + threadIdx.x;  // 0..131071
    if (idx < 1024) {
        int j = idx >> 2, g = idx & 3;
        PB[idx] = bih[g * 256 + j] + bhh[g * 256 + j];
    }
    int l = idx & 3;
    int gt = idx >> 2;
    int tid = gt & 511;
    int q = gt >> 9;                            // 0..63
    int i, c;
    if (q < 16)      { i = q >> 2; c = q & 3; }
    else if (q < 60) { int qq = q - 16; i = qq / 11; c = 4 + qq % 11; }
    else             { i = q - 60; c = 15; }
    int r = ((tid & 255) << 2) + i;
    int k = ((tid >> 8) << 7) + (c << 3) + (l << 1);
    _Float16 lo = (_Float16)Whh[r * 256 + k];
    _Float16 hi = (_Float16)Whh[r * 256 + k + 1];
    U32H2 x; x.h = h2t{lo, hi};
    WB[idx] = x.u;
}

// ---------------------------------------------------------------------------
// LSTM recurrence: 1 block/batch, 512 threads. NEW weight split: 128 KB LDS
// + 44-uint4 reg slab + 32 KB/step L2 stream (LDS was idle at 1 block/CU).
// g_in f16 gate-interleaved [t][j*4+g].
// ---------------------------------------------------------------------------
__global__ __launch_bounds__(512) void lstm_kernel(
    const _Float16* __restrict__ g_in, const uint4* __restrict__ WB4,
    _Float16* __restrict__ HALL16)
{
    const int b = blockIdx.x;
    const int tid = threadIdx.x;
    const int kh = tid >> 8, j4 = tid & 255;

    __shared__ uint4 WL4[8192];        // 128 KB
    __shared__ float gpart[2][1024];   // 8 KB
    __shared__ uint4 h2v[32];          // 512 B
    unsigned int* h2_s = (unsigned int*)h2v;

#pragma unroll
    for (int g = 0; g < 16; ++g) WL4[g * 512 + tid] = WB4[g * 512 + tid];
    uint4 wr[44];
#pragma unroll
    for (int q = 0; q < 44; ++q) wr[q] = WB4[(16 + q) * 512 + tid];
    if (tid < 128) h2_s[tid] = 0u;

    const _Float16* ginb = g_in + (size_t)b * 256 * 1024;
    uint2 gi = make_uint2(0u, 0u);
    if (tid < 256) gi = *(const uint2*)(ginb + tid * 4);
    float c_state = 0.f;
    const uint4* SW4 = WB4 + 60 * 512;
    __syncthreads();

    for (int t = 0; t < 256; ++t) {
        uint4 sw[4];
#pragma unroll
        for (int q = 0; q < 4; ++q) sw[q] = SW4[q * 512 + tid];

        float acc[4] = {0.f, 0.f, 0.f, 0.f};
#pragma unroll
        for (int c = 0; c < 16; ++c) {
            uint4 h4 = h2v[(kh << 4) + c];
            h2t hx = u2h(h4.x), hy = u2h(h4.y), hz = u2h(h4.z), hw = u2h(h4.w);
#pragma unroll
            for (int i = 0; i < 4; ++i) {
                uint4 w = (c < 4)  ? WL4[(((i << 2) + c)) * 512 + tid]
                        : (c < 15) ? wr[i * 11 + (c - 4)]
                                   : sw[i];
                acc[i] = __builtin_amdgcn_fdot2(u2h(w.x), hx, acc[i], false);
                acc[i] = __builtin_amdgcn_fdot2(u2h(w.y), hy, acc[i], false);
                acc[i] = __builtin_amdgcn_fdot2(u2h(w.z), hz, acc[i], false);
                acc[i] = __builtin_amdgcn_fdot2(u2h(w.w), hw, acc[i], false);
            }
        }
        *(float4*)&gpart[kh][j4 << 2] = make_float4(acc[0], acc[1], acc[2], acc[3]);
        __syncthreads();

        if (tid < 256) {
            int j = tid;
            h2t p0 = u2h(gi.x), p1 = u2h(gi.y);
            float ig = (float)p0.x + gpart[0][j]       + gpart[1][j];
            float fg = (float)p0.y + gpart[0][j + 256] + gpart[1][j + 256];
            float gg = (float)p1.x + gpart[0][j + 512] + gpart[1][j + 512];
            float og = (float)p1.y + gpart[0][j + 768] + gpart[1][j + 768];
            c_state = fsigm(fg) * c_state + fsigm(ig) * ftanh_(gg);
            float h = fsigm(og) * ftanh_(c_state);
            HALL16[((size_t)(b * 256 + t)) * 256 + j] = (_Float16)h;
            U32H2 hxp; hxp.h = h2t{(_Float16)h, (_Float16)0.f};
            unsigned int hu = hxp.u & 0xffffu;
            unsigned int other = (unsigned int)__shfl_xor((int)hu, 1);
            if ((j & 1) == 0) h2_s[j >> 1] = hu | (other << 16);
            int tn = (t < 255) ? (t + 1) : 255;
            gi = *(const uint2*)(ginb + (size_t)tn * 1024 + j * 4);
        }
        __syncthreads();
    }
}

// ---------------------------------------------------------------------------
// Pointer logits (R7 version): out = vsum - 2*sum_d v_d/(1+exp2(2.88539*(hp+ep)))
// ---------------------------------------------------------------------------
__global__ __launch_bounds__(256) void pointer_kernel(
    const float* __restrict__ HP, const float* __restrict__ EP,
    const float* __restrict__ v, float* __restrict__ out)
{
    int b = blockIdx.z, tt = blockIdx.y, it = blockIdx.x;
    __shared__ float hp_s[16][260];
    __shared__ float ep_s[16][260];
    __shared__ float v_s[256];
    __shared__ float red[4];
    int tid = threadIdx.x;
    const float cs = 2.88539008f;
    const float* hpb = HP + ((size_t)b * 256 + tt * 16) * 256;
    const float* epb = EP + ((size_t)b * 256 + it * 16) * 256;
#pragma unroll
    for (int l = 0; l < 4; ++l) {
        int idx = tid + l * 256;
        int r = idx >> 6, c4 = idx & 63;
        float4 hv = *(const float4*)(hpb + r * 256 + c4 * 4);
        hv.x *= cs; hv.y *= cs; hv.z *= cs; hv.w *= cs;
        *(float4*)&hp_s[r][c4 * 4] = hv;
        float4 ev = *(const float4*)(epb + r * 256 + c4 * 4);
        ev.x *= cs; ev.y *= cs; ev.z *= cs; ev.w *= cs;
        *(float4*)&ep_s[r][c4 * 4] = ev;
    }
    float vv = v[tid];
    v_s[tid] = vv;
    float vp = vv;
#pragma unroll
    for (int m = 1; m < 64; m <<= 1) vp += __shfl_xor(vp, m);
    if ((tid & 63) == 0) red[tid >> 6] = vp;
    __syncthreads();
    float vsum = red[0] + red[1] + red[2] + red[3];
    int tl = tid >> 4, il = tid & 15;
    float acc = 0.f;
#pragma unroll 4
    for (int d = 0; d < 256; ++d) {
        float sval = hp_s[tl][d] + ep_s[il][d];
        float r = frcp(1.0f + fexp2(sval));
        acc = fmaf(v_s[d], r, acc);
    }
    out[((size_t)b * 256 + tt * 16 + tl) * 256 + it * 16 + il] =
        vsum - 2.0f * acc;
}

// ---------------------------------------------------------------------------
extern "C" void kernel_launch(void* const* d_in, const int* in_sizes, int n_in,
                              void* d_out, int out_size, void* d_ws, size_t ws_size,
                              hipStream_t stream)
{
    const float* parts    = (const float*)d_in[0];
    const float* bin_info = (const float*)d_in[1];
    const int*   target   = (const int*)d_in[2];
    const float* pe_W1 = (const float*)d_in[3];
    const float* pe_b1 = (const float*)d_in[4];
    const float* pe_W2 = (const float*)d_in[5];
    const float* pe_b2 = (const float*)d_in[6];
    const float* be_W1 = (const float*)d_in[7];
    const float* be_b1 = (const float*)d_in[8];
    const float* be_W2 = (const float*)d_in[9];
    const float* be_b2 = (const float*)d_in[10];
    const float* pos_emb = (const float*)d_in[11];
    const float* tr_Wqkv = (const float*)d_in[12];
    const float* tr_bqkv = (const float*)d_in[13];
    const float* tr_Wo   = (const float*)d_in[14];
    const float* tr_bo   = (const float*)d_in[15];
    const float* tr_ln1_g = (const float*)d_in[16];
    const float* tr_ln1_b = (const float*)d_in[17];
    const float* tr_ff_W1 = (const float*)d_in[18];
    const float* tr_ff_b1 = (const float*)d_in[19];
    const float* tr_ff_W2 = (const float*)d_in[20];
    const float* tr_ff_b2 = (const float*)d_in[21];
    const float* tr_ln2_g = (const float*)d_in[22];
    const float* tr_ln2_b = (const float*)d_in[23];
    const float* lstm_Wih = (const float*)d_in[24];
    const float* lstm_Whh = (const float*)d_in[25];
    const float* lstm_bih = (const float*)d_in[26];
    const float* lstm_bhh = (const float*)d_in[27];
    const float* ptr_W = (const float*)d_in[28];
    const float* ptr_b = (const float*)d_in[29];
    const float* ptr_v = (const float*)d_in[30];

    // ---- workspace layout (floats) ----
    float* ws = (float*)d_ws;
    float* X     = ws;                        // 2,097,152
    float* S1    = X + 2097152;               // 8,388,608 (qkv/ff1/g_in f16)
    float* CF32  = S1 + 8388608;              // 2,097,152
    float* EPROJ = CF32 + 2097152;            // 2,097,152
    float* X16f  = EPROJ + 2097152;           // 1,048,576
    float* S2f   = X16f + 1048576;            // 1,048,576
    float* W16f  = S2f + 1048576;             // 1,048,576
    float* WBf   = W16f + 1048576;            // 131,072
    float* BBuf  = WBf + 131072;              // 2,048
    float* PB    = BBuf + 2048;               // 1,024

    _Float16* X16    = (_Float16*)X16f;
    _Float16* Xg16   = X16;                   // alias, live after eproj GEMM
    _Float16* S2h    = (_Float16*)S2f;
    _Float16* HALL16 = S2h;
    _Float16* S1h    = (_Float16*)S1;
    _Float16* W16    = (_Float16*)W16f;
    _Float16* Wqkv16 = W16;                   // 589,824
    _Float16* Wo16   = Wqkv16 + 589824;       // 196,608
    _Float16* Wff116 = Wo16 + 196608;         // 393,216
    _Float16* Wff216 = Wff116 + 393216;       // 393,216
    _Float16* Wih16  = Wff216 + 393216;       // 262,144 (gate-interleaved rows)
    _Float16* WpW16  = Wih16 + 262144;        // 65,536

    // ---- one-time weight conversions ----
    cvt_all_kernel<<<7424, 256, 0, stream>>>(tr_Wqkv, tr_Wo, tr_ff_W1, tr_ff_W2,
                                             lstm_Wih, ptr_W, W16);
    wcvt2_kernel<<<512, 256, 0, stream>>>(lstm_Whh, (unsigned int*)WBf,
                                          lstm_bih, lstm_bhh, PB);

    // ---- encoders ----
    bin_enc_kernel<<<32, 64, 0, stream>>>(bin_info, be_W1, be_b1, be_W2, be_b2, BBuf);
    part_enc_kernel<<<256, 128, 0, stream>>>(parts, pe_W1, pe_b1, pe_W2, pe_b2,
                                             BBuf, pos_emb, X, X16);

    // ---- transformer layers ----
    for (int l = 0; l < 3; ++l) {
        hgemm_kernel<64, 128, false, true><<<dim3(128, 6), 256, 0, stream>>>(
            X16, Wqkv16 + (size_t)l * 196608, tr_bqkv + l * 768, nullptr,
            S1h, 8192, 768, 256);
        attn_mfma_kernel<<<256, 256, 0, stream>>>(S1h, S2h);
        hgemm_kernel<64, 64, false, false><<<dim3(128, 4), 256, 0, stream>>>(
            S2h, Wo16 + (size_t)l * 65536, tr_bo + l * 256, nullptr,
            CF32, 8192, 256, 256);
        add_ln_kernel<<<2048, 256, 0, stream>>>(X, CF32, tr_ln1_g + l * 256,
                                                tr_ln1_b + l * 256, X16);
        hgemm_kernel<64, 128, true, true><<<dim3(128, 4), 256, 0, stream>>>(
            X16, Wff116 + (size_t)l * 131072, tr_ff_b1 + l * 512, nullptr,
            S1h, 8192, 512, 256);
        hgemm_kernel<64, 64, false, false><<<dim3(128, 4), 256, 0, stream>>>(
            S1h, Wff216 + (size_t)l * 131072, tr_ff_b2 + l * 256, nullptr,
            CF32, 8192, 256, 512);
        add_ln_kernel<<<2048, 256, 0, stream>>>(X, CF32, tr_ln2_g + l * 256,
                                                tr_ln2_b + l * 256, X16);
    }

    // ---- pointer decode ----
    hgemm_kernel<64, 64, false, false><<<dim3(128, 4), 256, 0, stream>>>(
        X16, WpW16, ptr_b, nullptr, EPROJ, 8192, 256, 256);
    gather_kernel<<<8192, 256, 0, stream>>>(X, target, Xg16);
    hgemm_kernel<64, 128, false, true><<<dim3(128, 8), 256, 0, stream>>>(
        Xg16, Wih16, PB, nullptr, S1h, 8192, 1024, 256);
    lstm_kernel<<<32, 512, 0, stream>>>(S1h, (const uint4*)WBf, HALL16);
    hgemm_kernel<64, 64, false, false><<<dim3(128, 4), 256, 0, stream>>>(
        HALL16, WpW16, ptr_b, nullptr, CF32, 8192, 256, 256);
    pointer_kernel<<<dim3(16, 16, 32), 256, 0, stream>>>(CF32, EPROJ, ptr_v,
                                                         (float*)d_out);
}